// Round 1
// baseline (879.521 us; speedup 1.0000x reference)
//
#include <hip/hip_runtime.h>
#include <stdint.h>

#define S_LEN  4096
#define HDIM   2048
#define NHEADS 32
#define NKVH   8
#define HDSZ   64
#define KVDIM  (NKVH * HDSZ)   // 512

typedef __bf16 v8bf16 __attribute__((ext_vector_type(8)));
typedef float  v4f32  __attribute__((ext_vector_type(4)));

__device__ __forceinline__ unsigned short f2bf(float f) {
    uint32_t u = __builtin_bit_cast(uint32_t, f);
    uint32_t r = (u + 0x7fffu + ((u >> 16) & 1u)) >> 16;  // round-to-nearest-even
    return (unsigned short)r;
}

__device__ __forceinline__ void async_load16(const void* g, void* l) {
    __builtin_amdgcn_global_load_lds((const __attribute__((address_space(1))) void*)g,
                                     (__attribute__((address_space(3))) void*)l,
                                     16, 0, 0);
}

// ---------------------------------------------------------------- fp32 -> bf16
__global__ void cvt_f32_bf16(const float* __restrict__ in,
                             unsigned short* __restrict__ out, int n4) {
    int i = blockIdx.x * blockDim.x + threadIdx.x;
    if (i >= n4) return;
    float4 f = ((const float4*)in)[i];
    ushort4 o;
    o.x = f2bf(f.x); o.y = f2bf(f.y); o.z = f2bf(f.z); o.w = f2bf(f.w);
    ((ushort4*)out)[i] = o;
}

// ------------------------------------------------- C = scale * (A @ B^T)
// A: [M,K] bf16 row-major, B: [N,K] bf16 row-major. 128x128 tile, BK=64.
// LDS k-groups XOR-swizzled (slot = kg ^ (row&7)), swizzle applied at the
// global fetch so global_load_lds's lane-contiguous LDS landing still works.
template <bool OUT_BF16>
__global__ __launch_bounds__(256)
void gemm_bt(const unsigned short* __restrict__ A,
             const unsigned short* __restrict__ B,
             void* __restrict__ Cout,
             int M, int N, int K, float scale)
{
    __shared__ unsigned short As[128 * 64];
    __shared__ unsigned short Bs[128 * 64];

    const int tid  = threadIdx.x;
    const int wave = tid >> 6;
    const int lane = tid & 63;
    const int lrow = lane & 15;
    const int quad = lane >> 4;

    const int m0 = blockIdx.x * 128;
    const int n0 = blockIdx.y * 128;
    const int wm = (wave >> 1) * 64;
    const int wn = (wave & 1) * 64;

    // staging: wave w covers tile rows [w*32, w*32+32), 4 instrs of 8 rows
    const int srow = wave * 32 + (lane >> 3);
    const int sg   = (lane & 7) ^ ((lane >> 3) & 7);   // swizzled k-group
    const size_t aOff = (size_t)(m0 + srow) * K + sg * 8;
    const size_t bOff = (size_t)(n0 + srow) * K + sg * 8;

    v4f32 acc[4][4];
#pragma unroll
    for (int mi = 0; mi < 4; ++mi)
#pragma unroll
        for (int ni = 0; ni < 4; ++ni)
#pragma unroll
            for (int r = 0; r < 4; ++r) acc[mi][ni][r] = 0.0f;

    for (int k0 = 0; k0 < K; k0 += 64) {
#pragma unroll
        for (int i = 0; i < 4; ++i) {
            async_load16(A + aOff + (size_t)(i * 8) * K + k0,
                         &As[(wave * 32 + i * 8) * 64]);
            async_load16(B + bOff + (size_t)(i * 8) * K + k0,
                         &Bs[(wave * 32 + i * 8) * 64]);
        }
        __syncthreads();
#pragma unroll
        for (int ks = 0; ks < 2; ++ks) {
            const int kg  = ks * 4 + quad;
            const int swz = (kg ^ (lrow & 7)) * 8;
            v8bf16 af[4], bfm[4];
#pragma unroll
            for (int mi = 0; mi < 4; ++mi)
                af[mi] = *(const v8bf16*)&As[(wm + mi * 16 + lrow) * 64 + swz];
#pragma unroll
            for (int ni = 0; ni < 4; ++ni)
                bfm[ni] = *(const v8bf16*)&Bs[(wn + ni * 16 + lrow) * 64 + swz];
#pragma unroll
            for (int mi = 0; mi < 4; ++mi)
#pragma unroll
                for (int ni = 0; ni < 4; ++ni)
                    acc[mi][ni] = __builtin_amdgcn_mfma_f32_16x16x32_bf16(
                        af[mi], bfm[ni], acc[mi][ni], 0, 0, 0);
        }
        __syncthreads();
    }

#pragma unroll
    for (int mi = 0; mi < 4; ++mi)
#pragma unroll
        for (int ni = 0; ni < 4; ++ni)
#pragma unroll
            for (int r = 0; r < 4; ++r) {
                const int row = m0 + wm + mi * 16 + quad * 4 + r;
                const int col = n0 + wn + ni * 16 + lrow;
                const float v = acc[mi][ni][r] * scale;
                if (OUT_BF16)
                    ((unsigned short*)Cout)[(size_t)row * N + col] = f2bf(v);
                else
                    ((float*)Cout)[(size_t)row * N + col] = v;
            }
}

// ------------------------------------------------- flash attention (causal)
// Q: [S, HDIM] bf16 (pre-scaled by 1/8), K/V: [S, KVDIM] bf16, O: [S, HDIM] bf16.
// Block: 128 Q rows x 1 head; 4 waves, each wave 32 Q rows; K-tile = 64.
__global__ __launch_bounds__(256)
void flash_attn(const unsigned short* __restrict__ Q,
                const unsigned short* __restrict__ K,
                const unsigned short* __restrict__ V,
                unsigned short* __restrict__ O)
{
    __shared__ unsigned short Qs[128 * 72];   // padded stride 72
    __shared__ unsigned short Ks[64 * 72];
    __shared__ unsigned short Vt[64 * 72];    // transposed: Vt[d][key]
    __shared__ unsigned short Ps[128 * 72];   // per-wave 32-row P buffers

    const int tid  = threadIdx.x;
    const int wave = tid >> 6;
    const int lane = tid & 63;
    const int lrow = lane & 15;
    const int quad = lane >> 4;

    const int h   = blockIdx.y;
    const int kvh = h >> 2;
    const int q0  = blockIdx.x * 128;

    // stage Q tile [128 x 64]
    for (int c = tid; c < 1024; c += 256) {
        const int r = c >> 3, c8 = c & 7;
        *(uint4*)&Qs[r * 72 + c8 * 8] =
            *(const uint4*)&Q[(size_t)(q0 + r) * HDIM + h * HDSZ + c8 * 8];
    }

    float m_s[2][4], l_s[2][4];
    v4f32 o_acc[2][4];
#pragma unroll
    for (int mi = 0; mi < 2; ++mi)
#pragma unroll
        for (int r = 0; r < 4; ++r) { m_s[mi][r] = -1e30f; l_s[mi][r] = 0.0f; }
#pragma unroll
    for (int mi = 0; mi < 2; ++mi)
#pragma unroll
        for (int dj = 0; dj < 4; ++dj)
#pragma unroll
            for (int r = 0; r < 4; ++r) o_acc[mi][dj][r] = 0.0f;

    const int rbase = q0 + wave * 32;
    const int njt = (q0 >> 6) + 2;   // keys [0, q0+128)

    for (int j = 0; j < njt; ++j) {
        const int k0 = j * 64;
        __syncthreads();   // previous iteration's reads done before restage
        // stage K tile [64 x 64]
        for (int c = tid; c < 512; c += 256) {
            const int r = c >> 3, c8 = c & 7;
            *(uint4*)&Ks[r * 72 + c8 * 8] =
                *(const uint4*)&K[(size_t)(k0 + r) * KVDIM + kvh * HDSZ + c8 * 8];
        }
        // stage V transposed: coalesced 16B read, scalar LDS scatter
        for (int c = tid; c < 512; c += 256) {
            const int key = c >> 3, d8 = c & 7;
            const uint4 dv = *(const uint4*)&V[(size_t)(k0 + key) * KVDIM + kvh * HDSZ + d8 * 8];
            const uint32_t vv[4] = {dv.x, dv.y, dv.z, dv.w};
#pragma unroll
            for (int t = 0; t < 4; ++t) {
                Vt[(d8 * 8 + 2 * t + 0) * 72 + key] = (unsigned short)(vv[t] & 0xffffu);
                Vt[(d8 * 8 + 2 * t + 1) * 72 + key] = (unsigned short)(vv[t] >> 16);
            }
        }
        __syncthreads();

        if (k0 <= rbase + 31) {          // skip fully-masked tiles for this wave
            // S = Q K^T  (2 mi x 4 nj tiles, K-dim 64 = 2 ksteps)
            v4f32 sc[2][4];
#pragma unroll
            for (int mi = 0; mi < 2; ++mi)
#pragma unroll
                for (int nj = 0; nj < 4; ++nj)
#pragma unroll
                    for (int r = 0; r < 4; ++r) sc[mi][nj][r] = 0.0f;
#pragma unroll
            for (int kk = 0; kk < 2; ++kk) {
                v8bf16 qa[2];
                qa[0] = *(const v8bf16*)&Qs[(wave * 32 + lrow) * 72 + kk * 32 + quad * 8];
                qa[1] = *(const v8bf16*)&Qs[(wave * 32 + 16 + lrow) * 72 + kk * 32 + quad * 8];
#pragma unroll
                for (int nj = 0; nj < 4; ++nj) {
                    const v8bf16 kb = *(const v8bf16*)&Ks[(nj * 16 + lrow) * 72 + kk * 32 + quad * 8];
                    sc[0][nj] = __builtin_amdgcn_mfma_f32_16x16x32_bf16(qa[0], kb, sc[0][nj], 0, 0, 0);
                    sc[1][nj] = __builtin_amdgcn_mfma_f32_16x16x32_bf16(qa[1], kb, sc[1][nj], 0, 0, 0);
                }
            }
            // causal mask (index-computed; the mask input is never read)
            if (k0 + 63 > rbase) {
#pragma unroll
                for (int mi = 0; mi < 2; ++mi)
#pragma unroll
                    for (int nj = 0; nj < 4; ++nj)
#pragma unroll
                        for (int r = 0; r < 4; ++r) {
                            const int qi = rbase + mi * 16 + quad * 4 + r;
                            const int ki = k0 + nj * 16 + lrow;
                            if (ki > qi) sc[mi][nj][r] = -1e30f;
                        }
            }
            // online softmax: row r held by 16 lanes of quad r>>2
            float rmax[2][4];
#pragma unroll
            for (int mi = 0; mi < 2; ++mi)
#pragma unroll
                for (int r = 0; r < 4; ++r) {
                    float v = sc[mi][0][r];
                    v = fmaxf(v, sc[mi][1][r]);
                    v = fmaxf(v, sc[mi][2][r]);
                    v = fmaxf(v, sc[mi][3][r]);
                    rmax[mi][r] = v;
                }
#pragma unroll
            for (int off = 1; off < 16; off <<= 1)
#pragma unroll
                for (int mi = 0; mi < 2; ++mi)
#pragma unroll
                    for (int r = 0; r < 4; ++r)
                        rmax[mi][r] = fmaxf(rmax[mi][r], __shfl_xor(rmax[mi][r], off));

            float alpha[2][4];
#pragma unroll
            for (int mi = 0; mi < 2; ++mi)
#pragma unroll
                for (int r = 0; r < 4; ++r) {
                    const float mn = fmaxf(m_s[mi][r], rmax[mi][r]);
                    alpha[mi][r] = __expf(m_s[mi][r] - mn);
                    m_s[mi][r] = mn;
                }
            float rsum[2][4] = {{0.f,0.f,0.f,0.f},{0.f,0.f,0.f,0.f}};
#pragma unroll
            for (int mi = 0; mi < 2; ++mi)
#pragma unroll
                for (int nj = 0; nj < 4; ++nj)
#pragma unroll
                    for (int r = 0; r < 4; ++r) {
                        const float p = __expf(sc[mi][nj][r] - m_s[mi][r]);
                        rsum[mi][r] += p;
                        Ps[(wave * 32 + mi * 16 + quad * 4 + r) * 72 + nj * 16 + lrow] = f2bf(p);
                    }
#pragma unroll
            for (int off = 1; off < 16; off <<= 1)
#pragma unroll
                for (int mi = 0; mi < 2; ++mi)
#pragma unroll
                    for (int r = 0; r < 4; ++r)
                        rsum[mi][r] += __shfl_xor(rsum[mi][r], off);
#pragma unroll
            for (int mi = 0; mi < 2; ++mi)
#pragma unroll
                for (int r = 0; r < 4; ++r)
                    l_s[mi][r] = l_s[mi][r] * alpha[mi][r] + rsum[mi][r];
#pragma unroll
            for (int mi = 0; mi < 2; ++mi)
#pragma unroll
                for (int dj = 0; dj < 4; ++dj)
#pragma unroll
                    for (int r = 0; r < 4; ++r)
                        o_acc[mi][dj][r] *= alpha[mi][r];

            // wave-private P LDS round-trip: C-layout -> A-layout
            asm volatile("s_waitcnt lgkmcnt(0)" ::: "memory");
#pragma unroll
            for (int kk = 0; kk < 2; ++kk) {
                v8bf16 pa[2];
                pa[0] = *(const v8bf16*)&Ps[(wave * 32 + lrow) * 72 + kk * 32 + quad * 8];
                pa[1] = *(const v8bf16*)&Ps[(wave * 32 + 16 + lrow) * 72 + kk * 32 + quad * 8];
#pragma unroll
                for (int dj = 0; dj < 4; ++dj) {
                    const v8bf16 vb = *(const v8bf16*)&Vt[(dj * 16 + lrow) * 72 + kk * 32 + quad * 8];
                    o_acc[0][dj] = __builtin_amdgcn_mfma_f32_16x16x32_bf16(pa[0], vb, o_acc[0][dj], 0, 0, 0);
                    o_acc[1][dj] = __builtin_amdgcn_mfma_f32_16x16x32_bf16(pa[1], vb, o_acc[1][dj], 0, 0, 0);
                }
            }
        }
    }

    // epilogue: O = o_acc / l, store bf16 [s][h*64+d]
#pragma unroll
    for (int mi = 0; mi < 2; ++mi)
#pragma unroll
        for (int r = 0; r < 4; ++r) {
            const float inv = 1.0f / l_s[mi][r];
            const int s = rbase + mi * 16 + quad * 4 + r;
#pragma unroll
            for (int dj = 0; dj < 4; ++dj) {
                const int d = dj * 16 + lrow;
                O[(size_t)s * HDIM + h * HDSZ + d] = f2bf(o_acc[mi][dj][r] * inv);
            }
        }
}

// ---------------------------------------------------------------- launcher
extern "C" void kernel_launch(void* const* d_in, const int* in_sizes, int n_in,
                              void* d_out, int out_size, void* d_ws, size_t ws_size,
                              hipStream_t stream)
{
    const float* x  = (const float*)d_in[0];
    // d_in[1] = attention_mask (exact causal) — recomputed from indices, never read
    const float* Wq = (const float*)d_in[2];
    const float* Wk = (const float*)d_in[3];
    const float* Wv = (const float*)d_in[4];
    const float* Wo = (const float*)d_in[5];
    float* out = (float*)d_out;

    // workspace layout (bf16 elements); AOb reuses xb (dead after V GEMM)
    unsigned short* xb  = (unsigned short*)d_ws;                 // 4096*2048
    unsigned short* Wqb = xb  + (size_t)S_LEN * HDIM;            // 2048*2048
    unsigned short* Wkb = Wqb + (size_t)HDIM * HDIM;             // 512*2048
    unsigned short* Wvb = Wkb + (size_t)KVDIM * HDIM;            // 512*2048
    unsigned short* Wob = Wvb + (size_t)KVDIM * HDIM;            // 2048*2048
    unsigned short* Qb  = Wob + (size_t)HDIM * HDIM;             // 4096*2048
    unsigned short* Kb  = Qb  + (size_t)S_LEN * HDIM;            // 4096*512
    unsigned short* Vb  = Kb  + (size_t)S_LEN * KVDIM;           // 4096*512
    unsigned short* AOb = xb;                                    // reuse

    auto cvt = [&](const float* src, unsigned short* dst, size_t n) {
        const int n4 = (int)(n / 4);
        cvt_f32_bf16<<<(n4 + 255) / 256, 256, 0, stream>>>(src, dst, n4);
    };
    cvt(x,  xb,  (size_t)S_LEN * HDIM);
    cvt(Wq, Wqb, (size_t)HDIM * HDIM);
    cvt(Wk, Wkb, (size_t)KVDIM * HDIM);
    cvt(Wv, Wvb, (size_t)KVDIM * HDIM);
    cvt(Wo, Wob, (size_t)HDIM * HDIM);

    // Q (scale 1/sqrt(64) folded in), K, V projections
    gemm_bt<true ><<<dim3(S_LEN / 128, HDIM / 128), 256, 0, stream>>>(
        xb, Wqb, Qb, S_LEN, HDIM, HDIM, 0.125f);
    gemm_bt<true ><<<dim3(S_LEN / 128, KVDIM / 128), 256, 0, stream>>>(
        xb, Wkb, Kb, S_LEN, KVDIM, HDIM, 1.0f);
    gemm_bt<true ><<<dim3(S_LEN / 128, KVDIM / 128), 256, 0, stream>>>(
        xb, Wvb, Vb, S_LEN, KVDIM, HDIM, 1.0f);

    flash_attn<<<dim3(S_LEN / 128, NHEADS), 256, 0, stream>>>(Qb, Kb, Vb, AOb);

    gemm_bt<false><<<dim3(S_LEN / 128, HDIM / 128), 256, 0, stream>>>(
        AOb, Wob, out, S_LEN, HDIM, HDIM, 1.0f);
}

// Round 2
// 448.735 us; speedup vs baseline: 1.9600x; 1.9600x over previous
//
#include <hip/hip_runtime.h>
#include <stdint.h>

#define S_LEN  4096
#define HDIM   2048
#define NHEADS 32
#define NKVH   8
#define HDSZ   64
#define KVDIM  (NKVH * HDSZ)   // 512

typedef __bf16 v8bf16 __attribute__((ext_vector_type(8)));
typedef short  v4s    __attribute__((ext_vector_type(4)));
typedef float  v4f32  __attribute__((ext_vector_type(4)));

__device__ __forceinline__ unsigned short f2bf(float f) {
    uint32_t u = __builtin_bit_cast(uint32_t, f);
    uint32_t r = (u + 0x7fffu + ((u >> 16) & 1u)) >> 16;  // round-to-nearest-even
    return (unsigned short)r;
}
__device__ __forceinline__ short f2bf_fast(float f) {     // approx-RNE (no tie fix)
    return (short)((__builtin_bit_cast(uint32_t, f) + 0x8000u) >> 16);
}

__device__ __forceinline__ void async_load16(const void* g, void* l) {
    __builtin_amdgcn_global_load_lds((const __attribute__((address_space(1))) void*)g,
                                     (__attribute__((address_space(3))) void*)l,
                                     16, 0, 0);
}

// ---------------------------------------------------------------- fp32 -> bf16
__global__ void cvt_f32_bf16(const float* __restrict__ in,
                             unsigned short* __restrict__ out, int n4) {
    int i = blockIdx.x * blockDim.x + threadIdx.x;
    if (i >= n4) return;
    float4 f = ((const float4*)in)[i];
    ushort4 o;
    o.x = f2bf(f.x); o.y = f2bf(f.y); o.z = f2bf(f.z); o.w = f2bf(f.w);
    ((ushort4*)out)[i] = o;
}

// ------------------------------------------------- C = scale * (A @ B^T)
// A: [M,K] bf16 row-major, B: [N,K] bf16 row-major. 128x128 tile, BK=64.
// XOR-swizzled LDS k-groups, swizzle applied at the global fetch so
// global_load_lds's lane-contiguous landing still works.
template <bool OUT_BF16>
__global__ __launch_bounds__(256)
void gemm_bt(const unsigned short* __restrict__ A,
             const unsigned short* __restrict__ B,
             void* __restrict__ Cout,
             int M, int N, int K, float scale)
{
    __shared__ unsigned short As[128 * 64];
    __shared__ unsigned short Bs[128 * 64];

    const int tid  = threadIdx.x;
    const int wave = tid >> 6;
    const int lane = tid & 63;
    const int lrow = lane & 15;
    const int quad = lane >> 4;

    const int m0 = blockIdx.x * 128;
    const int n0 = blockIdx.y * 128;
    const int wm = (wave >> 1) * 64;
    const int wn = (wave & 1) * 64;

    const int srow = wave * 32 + (lane >> 3);
    const int sg   = (lane & 7) ^ ((lane >> 3) & 7);   // swizzled k-group
    const size_t aOff = (size_t)(m0 + srow) * K + sg * 8;
    const size_t bOff = (size_t)(n0 + srow) * K + sg * 8;

    v4f32 acc[4][4];
#pragma unroll
    for (int mi = 0; mi < 4; ++mi)
#pragma unroll
        for (int ni = 0; ni < 4; ++ni)
#pragma unroll
            for (int r = 0; r < 4; ++r) acc[mi][ni][r] = 0.0f;

    for (int k0 = 0; k0 < K; k0 += 64) {
#pragma unroll
        for (int i = 0; i < 4; ++i) {
            async_load16(A + aOff + (size_t)(i * 8) * K + k0,
                         &As[(wave * 32 + i * 8) * 64]);
            async_load16(B + bOff + (size_t)(i * 8) * K + k0,
                         &Bs[(wave * 32 + i * 8) * 64]);
        }
        __syncthreads();
#pragma unroll
        for (int ks = 0; ks < 2; ++ks) {
            const int kg  = ks * 4 + quad;
            const int swz = (kg ^ (lrow & 7)) * 8;
            v8bf16 af[4], bfm[4];
#pragma unroll
            for (int mi = 0; mi < 4; ++mi)
                af[mi] = *(const v8bf16*)&As[(wm + mi * 16 + lrow) * 64 + swz];
#pragma unroll
            for (int ni = 0; ni < 4; ++ni)
                bfm[ni] = *(const v8bf16*)&Bs[(wn + ni * 16 + lrow) * 64 + swz];
#pragma unroll
            for (int mi = 0; mi < 4; ++mi)
#pragma unroll
                for (int ni = 0; ni < 4; ++ni)
                    acc[mi][ni] = __builtin_amdgcn_mfma_f32_16x16x32_bf16(
                        af[mi], bfm[ni], acc[mi][ni], 0, 0, 0);
        }
        __syncthreads();
    }

#pragma unroll
    for (int mi = 0; mi < 4; ++mi)
#pragma unroll
        for (int ni = 0; ni < 4; ++ni)
#pragma unroll
            for (int r = 0; r < 4; ++r) {
                const int row = m0 + wm + mi * 16 + quad * 4 + r;
                const int col = n0 + wn + ni * 16 + lrow;
                const float v = acc[mi][ni][r] * scale;
                if (OUT_BF16)
                    ((unsigned short*)Cout)[(size_t)row * N + col] = f2bf(v);
                else
                    ((float*)Cout)[(size_t)row * N + col] = v;
            }
}

// ------------------------------------------------- flash attention (causal)
// Q: [S, HDIM] bf16 (pre-scaled 1/8). K: [S, KVDIM] bf16. Vt: [KVDIM, S] bf16.
// O: [S, HDIM] bf16. Block: 128 Q rows x 1 head; each wave owns 32 Q rows.
// S^T = K*Q^T so that P's C-layout IS the B-operand layout of 16x16x16 MFMA:
// PV needs no transpose at all. O^T = V^T * P^T, accumulated in C-layout with
// q on lane&15 (where m/l live -> shuffle-free rescale).
__global__ __launch_bounds__(256)
void flash_attn(const unsigned short* __restrict__ Q,
                const unsigned short* __restrict__ K,
                const unsigned short* __restrict__ Vt,
                unsigned short* __restrict__ O)
{
    __shared__ unsigned short smem[16384];          // 32 KB
    unsigned short* Qs = smem;                      // 128 x 64 (swizzled)
    unsigned short* Ks = smem + 128 * 64;           // 64 x 64 (swizzled)
    unsigned short* Vs = smem + 128 * 64 + 64 * 64; // 64 x 64 (V^T rows, swizzled)

    const int tid  = threadIdx.x;
    const int wave = tid >> 6;
    const int lane = tid & 63;
    const int lrow = lane & 15;
    const int quad = lane >> 4;

    const int h   = blockIdx.x;
    const int kvh = h >> 2;
    const int q0  = (gridDim.y - 1 - blockIdx.y) * 128;   // heavy blocks first

    const int srow8 = lane >> 3;             // row within 8-row staging group
    const int sgrp  = (lane & 7) ^ srow8;    // swizzled source col-group

    // stage Q tile [128 x 64] via global_load_lds
    {
        const size_t gq = (size_t)(q0 + wave * 32 + srow8) * HDIM + h * HDSZ + sgrp * 8;
#pragma unroll
        for (int i = 0; i < 4; ++i)
            async_load16(Q + gq + (size_t)(i * 8) * HDIM, &Qs[(wave * 32 + i * 8) * 64]);
    }

    float m_s[2] = {-1e30f, -1e30f};
    float l_s[2] = {0.0f, 0.0f};
    v4f32 o_acc[2][4];                       // [mi][dj]: col q=lane&15+16mi, row d=quad*4+r+16dj
#pragma unroll
    for (int mi = 0; mi < 2; ++mi)
#pragma unroll
        for (int dj = 0; dj < 4; ++dj)
#pragma unroll
            for (int r = 0; r < 4; ++r) o_acc[mi][dj][r] = 0.0f;

    const int rbase = q0 + wave * 32;
    const int njt   = (q0 >> 6) + 2;         // keys [0, q0+128)

    for (int j = 0; j < njt; ++j) {
        const int k0 = j * 64;
        __syncthreads();                     // prev reads done before restage
        {
            const size_t gk = (size_t)(k0 + wave * 16 + srow8) * KVDIM + kvh * HDSZ + sgrp * 8;
            async_load16(K + gk,              &Ks[(wave * 16) * 64]);
            async_load16(K + gk + 8 * KVDIM,  &Ks[(wave * 16 + 8) * 64]);
            const size_t gv = (size_t)(kvh * HDSZ + wave * 16 + srow8) * S_LEN + k0 + sgrp * 8;
            async_load16(Vt + gv,             &Vs[(wave * 16) * 64]);
            async_load16(Vt + gv + 8 * S_LEN, &Vs[(wave * 16 + 8) * 64]);
        }
        __syncthreads();

        if (k0 > rbase + 31) continue;       // fully masked for this wave

        // S^T = K · Q^T : st[mi][nj], col q = lane&15+16mi, row key = quad*4+r+16nj
        v4f32 st[2][4];
#pragma unroll
        for (int mi = 0; mi < 2; ++mi)
#pragma unroll
            for (int nj = 0; nj < 4; ++nj)
#pragma unroll
                for (int r = 0; r < 4; ++r) st[mi][nj][r] = 0.0f;
#pragma unroll
        for (int kk = 0; kk < 2; ++kk) {
            const int swz = ((kk * 4 + quad) ^ (lrow & 7)) * 8;
            v8bf16 qa[2];
            qa[0] = *(const v8bf16*)&Qs[(wave * 32 + lrow) * 64 + swz];
            qa[1] = *(const v8bf16*)&Qs[(wave * 32 + 16 + lrow) * 64 + swz];
#pragma unroll
            for (int nj = 0; nj < 4; ++nj) {
                const v8bf16 kb = *(const v8bf16*)&Ks[(nj * 16 + lrow) * 64 + swz];
                st[0][nj] = __builtin_amdgcn_mfma_f32_16x16x32_bf16(kb, qa[0], st[0][nj], 0, 0, 0);
                st[1][nj] = __builtin_amdgcn_mfma_f32_16x16x32_bf16(kb, qa[1], st[1][nj], 0, 0, 0);
            }
        }

        // causal mask (computed from indices)
        if (k0 + 63 > rbase) {
#pragma unroll
            for (int mi = 0; mi < 2; ++mi) {
                const int qi = rbase + mi * 16 + lrow;
#pragma unroll
                for (int nj = 0; nj < 4; ++nj)
#pragma unroll
                    for (int r = 0; r < 4; ++r) {
                        const int ki = k0 + nj * 16 + quad * 4 + r;
                        if (ki > qi) st[mi][nj][r] = -1e30f;
                    }
            }
        }

        // online softmax + pack P (C-layout == B-layout of 16x16x16 MFMA)
        v4s pk[2][4];
#pragma unroll
        for (int mi = 0; mi < 2; ++mi) {
            float tm = st[mi][0][0];
#pragma unroll
            for (int nj = 0; nj < 4; ++nj)
#pragma unroll
                for (int r = 0; r < 4; ++r) tm = fmaxf(tm, st[mi][nj][r]);
            tm = fmaxf(tm, __shfl_xor(tm, 16));
            tm = fmaxf(tm, __shfl_xor(tm, 32));
            const float mn = fmaxf(m_s[mi], tm);
            const float al = __expf(m_s[mi] - mn);
            m_s[mi] = mn;
            float rs = 0.0f;
#pragma unroll
            for (int nj = 0; nj < 4; ++nj) {
                float p0 = __expf(st[mi][nj][0] - mn);
                float p1 = __expf(st[mi][nj][1] - mn);
                float p2 = __expf(st[mi][nj][2] - mn);
                float p3 = __expf(st[mi][nj][3] - mn);
                rs += (p0 + p1) + (p2 + p3);
                v4s t;
                t[0] = f2bf_fast(p0); t[1] = f2bf_fast(p1);
                t[2] = f2bf_fast(p2); t[3] = f2bf_fast(p3);
                pk[mi][nj] = t;
            }
            rs += __shfl_xor(rs, 16);
            rs += __shfl_xor(rs, 32);
            l_s[mi] = l_s[mi] * al + rs;
#pragma unroll
            for (int dj = 0; dj < 4; ++dj)
#pragma unroll
                for (int r = 0; r < 4; ++r) o_acc[mi][dj][r] *= al;
        }

        // O^T += V^T · P^T  (A-frag = ds_read_b64 from swizzled V^T tile)
#pragma unroll
        for (int t = 0; t < 4; ++t) {
            v4s va[4];
#pragma unroll
            for (int dj = 0; dj < 4; ++dj)
                va[dj] = *(const v4s*)&Vs[(dj * 16 + lrow) * 64 +
                                          (((2 * t + (quad >> 1)) ^ (lrow & 7)) * 8) + (quad & 1) * 4];
#pragma unroll
            for (int dj = 0; dj < 4; ++dj) {
                o_acc[0][dj] = __builtin_amdgcn_mfma_f32_16x16x16bf16_1k(va[dj], pk[0][t], o_acc[0][dj], 0, 0, 0);
                o_acc[1][dj] = __builtin_amdgcn_mfma_f32_16x16x16bf16_1k(va[dj], pk[1][t], o_acc[1][dj], 0, 0, 0);
            }
        }
    }

    // epilogue: transpose O^T -> O through LDS, then coalesced 16B stores
    __syncthreads();
    unsigned short* Os = smem;               // reuse: 128 x 72 (16B-aligned rows)
#pragma unroll
    for (int mi = 0; mi < 2; ++mi) {
        const float inv = 1.0f / l_s[mi];
#pragma unroll
        for (int dj = 0; dj < 4; ++dj)
#pragma unroll
            for (int r = 0; r < 4; ++r)
                Os[(wave * 32 + mi * 16 + lrow) * 72 + dj * 16 + quad * 4 + r] =
                    f2bf(o_acc[mi][dj][r] * inv);
    }
    __syncthreads();
#pragma unroll
    for (int i = 0; i < 4; ++i) {
        const int idx = i * 256 + tid;
        const int row = idx >> 3, c8 = idx & 7;
        const uint4 vv = *(const uint4*)&Os[row * 72 + c8 * 8];
        *(uint4*)&O[(size_t)(q0 + row) * HDIM + h * HDSZ + c8 * 8] = vv;
    }
}

// ---------------------------------------------------------------- launcher
extern "C" void kernel_launch(void* const* d_in, const int* in_sizes, int n_in,
                              void* d_out, int out_size, void* d_ws, size_t ws_size,
                              hipStream_t stream)
{
    const float* x  = (const float*)d_in[0];
    // d_in[1] = attention_mask (exact causal) — recomputed from indices, never read
    const float* Wq = (const float*)d_in[2];
    const float* Wk = (const float*)d_in[3];
    const float* Wv = (const float*)d_in[4];
    const float* Wo = (const float*)d_in[5];
    float* out = (float*)d_out;

    unsigned short* xb  = (unsigned short*)d_ws;                 // 4096*2048
    unsigned short* Wqb = xb  + (size_t)S_LEN * HDIM;            // 2048*2048
    unsigned short* Wkb = Wqb + (size_t)HDIM * HDIM;             // 512*2048
    unsigned short* Wvb = Wkb + (size_t)KVDIM * HDIM;            // 512*2048
    unsigned short* Wob = Wvb + (size_t)KVDIM * HDIM;            // 2048*2048
    unsigned short* Qb  = Wob + (size_t)HDIM * HDIM;             // 4096*2048
    unsigned short* Kb  = Qb  + (size_t)S_LEN * HDIM;            // 4096*512
    unsigned short* Vtb = Kb  + (size_t)S_LEN * KVDIM;           // 512*4096 (V^T)
    unsigned short* AOb = xb;                                    // reuse

    auto cvt = [&](const float* src, unsigned short* dst, size_t n) {
        const int n4 = (int)(n / 4);
        cvt_f32_bf16<<<(n4 + 255) / 256, 256, 0, stream>>>(src, dst, n4);
    };
    cvt(x,  xb,  (size_t)S_LEN * HDIM);
    cvt(Wq, Wqb, (size_t)HDIM * HDIM);
    cvt(Wk, Wkb, (size_t)KVDIM * HDIM);
    cvt(Wv, Wvb, (size_t)KVDIM * HDIM);
    cvt(Wo, Wob, (size_t)HDIM * HDIM);

    // Q (1/sqrt(64) folded), K projections; V projection computed TRANSPOSED
    // (operands swapped: C = Wv · x^T = V^T [512 x 4096]) for free.
    gemm_bt<true ><<<dim3(S_LEN / 128, HDIM / 128), 256, 0, stream>>>(
        xb, Wqb, Qb, S_LEN, HDIM, HDIM, 0.125f);
    gemm_bt<true ><<<dim3(S_LEN / 128, KVDIM / 128), 256, 0, stream>>>(
        xb, Wkb, Kb, S_LEN, KVDIM, HDIM, 1.0f);
    gemm_bt<true ><<<dim3(KVDIM / 128, S_LEN / 128), 256, 0, stream>>>(
        Wvb, xb, Vtb, KVDIM, S_LEN, HDIM, 1.0f);

    flash_attn<<<dim3(NHEADS, S_LEN / 128), 256, 0, stream>>>(Qb, Kb, Vtb, AOb);

    gemm_bt<false><<<dim3(S_LEN / 128, HDIM / 128), 256, 0, stream>>>(
        AOb, Wob, out, S_LEN, HDIM, HDIM, 1.0f);
}

// Round 3
// 419.629 us; speedup vs baseline: 2.0959x; 1.0694x over previous
//
#include <hip/hip_runtime.h>
#include <stdint.h>

#define S_LEN  4096
#define HDIM   2048
#define NHEADS 32
#define NKVH   8
#define HDSZ   64
#define KVDIM  (NKVH * HDSZ)   // 512
#define QKN    (HDIM + KVDIM)  // 2560 fused Q|K projection width

typedef __bf16 v8bf16 __attribute__((ext_vector_type(8)));
typedef short  v4s    __attribute__((ext_vector_type(4)));
typedef float  v4f32  __attribute__((ext_vector_type(4)));

__device__ __forceinline__ unsigned short f2bf(float f) {
    uint32_t u = __builtin_bit_cast(uint32_t, f);
    uint32_t r = (u + 0x7fffu + ((u >> 16) & 1u)) >> 16;  // RNE
    return (unsigned short)r;
}

// pack two floats -> bf16x2 in one uint32 (HW cvt if available)
__device__ __forceinline__ uint32_t pack_bf16(float a, float b) {
#if __has_builtin(__builtin_amdgcn_cvt_pk_bf16_f32)
    auto r = __builtin_amdgcn_cvt_pk_bf16_f32(a, b);
    return __builtin_bit_cast(uint32_t, r);
#else
    uint32_t ua = __builtin_bit_cast(uint32_t, a) + 0x8000u;
    uint32_t ub = __builtin_bit_cast(uint32_t, b) + 0x8000u;
    return (ua >> 16) | (ub & 0xffff0000u);
#endif
}

__device__ __forceinline__ float fast_exp2(float x) {
#if __has_builtin(__builtin_amdgcn_exp2f)
    return __builtin_amdgcn_exp2f(x);
#else
    float r; asm("v_exp_f32 %0, %1" : "=v"(r) : "v"(x)); return r;
#endif
}

__device__ __forceinline__ void async_load16(const void* g, void* l) {
    __builtin_amdgcn_global_load_lds((const __attribute__((address_space(1))) void*)g,
                                     (__attribute__((address_space(3))) void*)l,
                                     16, 0, 0);
}

// ---------------------------------------------------------------- fp32 -> bf16 (scaled)
__global__ void cvt_f32_bf16(const float* __restrict__ in,
                             unsigned short* __restrict__ out, int n4, float scale) {
    int i = blockIdx.x * blockDim.x + threadIdx.x;
    if (i >= n4) return;
    float4 f = ((const float4*)in)[i];
    uint2 o;
    o.x = pack_bf16(f.x * scale, f.y * scale);
    o.y = pack_bf16(f.z * scale, f.w * scale);
    ((uint2*)out)[i] = o;
}

// ------------------------------------------------- C = scale * (A @ B^T)
// A: [M,K] bf16 row-major, B: [N,K] bf16 row-major. 128x128 tile, BK=64.
// XOR-swizzled LDS k-groups applied at the global fetch.
template <bool OUT_BF16>
__global__ __launch_bounds__(256)
void gemm_bt(const unsigned short* __restrict__ A,
             const unsigned short* __restrict__ B,
             void* __restrict__ Cout,
             int M, int N, int K, float scale)
{
    __shared__ unsigned short As[128 * 64];
    __shared__ unsigned short Bs[128 * 64];

    const int tid  = threadIdx.x;
    const int wave = tid >> 6;
    const int lane = tid & 63;
    const int lrow = lane & 15;
    const int quad = lane >> 4;

    const int m0 = blockIdx.x * 128;
    const int n0 = blockIdx.y * 128;
    const int wm = (wave >> 1) * 64;
    const int wn = (wave & 1) * 64;

    const int srow = wave * 32 + (lane >> 3);
    const int sg   = (lane & 7) ^ ((lane >> 3) & 7);
    const size_t aOff = (size_t)(m0 + srow) * K + sg * 8;
    const size_t bOff = (size_t)(n0 + srow) * K + sg * 8;

    v4f32 acc[4][4];
#pragma unroll
    for (int mi = 0; mi < 4; ++mi)
#pragma unroll
        for (int ni = 0; ni < 4; ++ni)
#pragma unroll
            for (int r = 0; r < 4; ++r) acc[mi][ni][r] = 0.0f;

    for (int k0 = 0; k0 < K; k0 += 64) {
#pragma unroll
        for (int i = 0; i < 4; ++i) {
            async_load16(A + aOff + (size_t)(i * 8) * K + k0,
                         &As[(wave * 32 + i * 8) * 64]);
            async_load16(B + bOff + (size_t)(i * 8) * K + k0,
                         &Bs[(wave * 32 + i * 8) * 64]);
        }
        __syncthreads();
#pragma unroll
        for (int ks = 0; ks < 2; ++ks) {
            const int kg  = ks * 4 + quad;
            const int swz = (kg ^ (lrow & 7)) * 8;
            v8bf16 af[4], bfm[4];
#pragma unroll
            for (int mi = 0; mi < 4; ++mi)
                af[mi] = *(const v8bf16*)&As[(wm + mi * 16 + lrow) * 64 + swz];
#pragma unroll
            for (int ni = 0; ni < 4; ++ni)
                bfm[ni] = *(const v8bf16*)&Bs[(wn + ni * 16 + lrow) * 64 + swz];
#pragma unroll
            for (int mi = 0; mi < 4; ++mi)
#pragma unroll
                for (int ni = 0; ni < 4; ++ni)
                    acc[mi][ni] = __builtin_amdgcn_mfma_f32_16x16x32_bf16(
                        af[mi], bfm[ni], acc[mi][ni], 0, 0, 0);
        }
        __syncthreads();
    }

#pragma unroll
    for (int mi = 0; mi < 4; ++mi)
#pragma unroll
        for (int ni = 0; ni < 4; ++ni)
#pragma unroll
            for (int r = 0; r < 4; ++r) {
                const int row = m0 + wm + mi * 16 + quad * 4 + r;
                const int col = n0 + wn + ni * 16 + lrow;
                const float v = acc[mi][ni][r] * scale;
                if (OUT_BF16)
                    ((unsigned short*)Cout)[(size_t)row * N + col] = f2bf(v);
                else
                    ((float*)Cout)[(size_t)row * N + col] = v;
            }
}

// ------------------------------------------------- flash attention (causal)
// QK: [S, 2560] bf16 — Q in cols [0,2048) pre-scaled by log2(e)/8, K in cols
// [2048,2560). Vt: [KVDIM, S] bf16. O: [S, HDIM] bf16.
// Block: 128 Q rows x 1 head, 4 waves x 32 Q rows, K-tile = 128.
// S^T = K*Q^T; P C-layout == B-layout of 16x16x16 MFMA (no transpose).
// O^T = V^T*P^T; softmax denominator accumulated by MFMA with a ones-vector.
__global__ __launch_bounds__(256)
void flash_attn(const unsigned short* __restrict__ QK,
                const unsigned short* __restrict__ Vt,
                unsigned short* __restrict__ O)
{
    __shared__ unsigned short smem[24576];          // 48 KB
    unsigned short* Qs = smem;                      // 128 x 64  (swizzled by row&7)
    unsigned short* Ks = smem + 128 * 64;           // 128 x 64  (swizzled by row&7)
    unsigned short* Vs = smem + 2 * 128 * 64;       // 64 x 128  (swizzled by row&15)

    const int tid  = threadIdx.x;
    const int wave = tid >> 6;
    const int lane = tid & 63;
    const int lrow = lane & 15;
    const int quad = lane >> 4;

    const int h   = blockIdx.x;
    const int kvh = h >> 2;
    const int q0  = (gridDim.y - 1 - blockIdx.y) * 128;   // heavy blocks first

    const int srow8 = lane >> 3;
    const int sgrp  = (lane & 7) ^ srow8;

    // stage Q tile [128 x 64]
    {
        const size_t gq = (size_t)(q0 + wave * 32 + srow8) * QKN + h * HDSZ + sgrp * 8;
#pragma unroll
        for (int i = 0; i < 4; ++i)
            async_load16(QK + gq + (size_t)(i * 8) * QKN, &Qs[(wave * 32 + i * 8) * 64]);
    }

    float m_s[2] = {-1e30f, -1e30f};
    v4f32 o_acc[2][4], l_acc[2];
#pragma unroll
    for (int mi = 0; mi < 2; ++mi) {
#pragma unroll
        for (int r = 0; r < 4; ++r) l_acc[mi][r] = 0.0f;
#pragma unroll
        for (int dj = 0; dj < 4; ++dj)
#pragma unroll
            for (int r = 0; r < 4; ++r) o_acc[mi][dj][r] = 0.0f;
    }
    const v4s v_one = {0x3F80, 0x3F80, 0x3F80, 0x3F80};   // bf16 1.0 x4

    const int rbase = q0 + wave * 32;
    const int njt   = (q0 >> 7) + 1;          // keys [0, q0+128)

    for (int j = 0; j < njt; ++j) {
        const int k0 = j * 128;
        __syncthreads();                      // prev reads done before restage
        {   // K tile: 128 rows x 64, wave stages rows [wave*32, wave*32+32)
            const size_t gk = (size_t)(k0 + wave * 32 + srow8) * QKN
                              + HDIM + kvh * HDSZ + sgrp * 8;
#pragma unroll
            for (int i = 0; i < 4; ++i)
                async_load16(QK + gk + (size_t)(i * 8) * QKN, &Ks[(wave * 32 + i * 8) * 64]);
            // V^T tile: 64 d-rows x 128 keys, wave stages rows [wave*16, +16)
            const int vr = lane >> 4;                  // 4 rows per instr
            const int vg = lane & 15;                  // 16 col groups of 8
#pragma unroll
            for (int i = 0; i < 4; ++i) {
                const int rloc = i * 4 + vr;           // row & 15 within tile
                const size_t gv = (size_t)(kvh * HDSZ + wave * 16 + rloc) * S_LEN
                                  + k0 + (size_t)(vg ^ rloc) * 8;
                async_load16(Vt + gv, &Vs[(wave * 16 + i * 4) * 128]);
            }
        }
        __syncthreads();

        if (k0 > rbase + 31) continue;        // fully masked for this wave

        // S^T = K · Q^T : st[mi][nj], col q = lrow+16mi, row key = 16nj+quad*4+r
        v4f32 st[2][8];
#pragma unroll
        for (int mi = 0; mi < 2; ++mi)
#pragma unroll
            for (int nj = 0; nj < 8; ++nj)
#pragma unroll
                for (int r = 0; r < 4; ++r) st[mi][nj][r] = 0.0f;
#pragma unroll
        for (int kk = 0; kk < 2; ++kk) {
            const int swz = ((kk * 4 + quad) ^ (lrow & 7)) * 8;
            v8bf16 qa[2];
            qa[0] = *(const v8bf16*)&Qs[(wave * 32 + lrow) * 64 + swz];
            qa[1] = *(const v8bf16*)&Qs[(wave * 32 + 16 + lrow) * 64 + swz];
#pragma unroll
            for (int nj = 0; nj < 8; ++nj) {
                const v8bf16 kb = *(const v8bf16*)&Ks[(nj * 16 + lrow) * 64 + swz];
                st[0][nj] = __builtin_amdgcn_mfma_f32_16x16x32_bf16(kb, qa[0], st[0][nj], 0, 0, 0);
                st[1][nj] = __builtin_amdgcn_mfma_f32_16x16x32_bf16(kb, qa[1], st[1][nj], 0, 0, 0);
            }
        }

        // causal mask (only the diagonal tile needs it)
        if (k0 + 127 > rbase) {
#pragma unroll
            for (int mi = 0; mi < 2; ++mi) {
                const int qi = rbase + mi * 16 + lrow;
#pragma unroll
                for (int nj = 0; nj < 8; ++nj) {
                    const int kib = k0 + nj * 16 + quad * 4;
#pragma unroll
                    for (int r = 0; r < 4; ++r)
                        if (kib + r > qi) st[mi][nj][r] = -1e30f;
                }
            }
        }

        // online softmax in log2 domain + pack P
        v4s pk[2][8];
#pragma unroll
        for (int mi = 0; mi < 2; ++mi) {
            float tm = st[mi][0][0];
#pragma unroll
            for (int nj = 0; nj < 8; ++nj)
#pragma unroll
                for (int r = 0; r < 4; ++r) tm = fmaxf(tm, st[mi][nj][r]);
            tm = fmaxf(tm, __shfl_xor(tm, 16));
            tm = fmaxf(tm, __shfl_xor(tm, 32));
            const float mn = fmaxf(m_s[mi], tm);
            const float al = fast_exp2(m_s[mi] - mn);
            m_s[mi] = mn;
#pragma unroll
            for (int nj = 0; nj < 8; ++nj) {
                const float p0 = fast_exp2(st[mi][nj][0] - mn);
                const float p1 = fast_exp2(st[mi][nj][1] - mn);
                const float p2 = fast_exp2(st[mi][nj][2] - mn);
                const float p3 = fast_exp2(st[mi][nj][3] - mn);
                uint2 u;
                u.x = pack_bf16(p0, p1);
                u.y = pack_bf16(p2, p3);
                pk[mi][nj] = __builtin_bit_cast(v4s, u);
            }
#pragma unroll
            for (int r = 0; r < 4; ++r) l_acc[mi][r] *= al;
#pragma unroll
            for (int dj = 0; dj < 4; ++dj)
#pragma unroll
                for (int r = 0; r < 4; ++r) o_acc[mi][dj][r] *= al;
        }

        // O^T += V^T · P^T ; l += 1^T · P^T  (A-frags from swizzled V^T tile)
#pragma unroll
        for (int t = 0; t < 8; ++t) {
            v4s va[4];
#pragma unroll
            for (int dj = 0; dj < 4; ++dj)
                va[dj] = *(const v4s*)&Vs[(dj * 16 + lrow) * 128 +
                                          (((t * 2 + (quad >> 1)) ^ lrow) * 8) + (quad & 1) * 4];
#pragma unroll
            for (int dj = 0; dj < 4; ++dj) {
                o_acc[0][dj] = __builtin_amdgcn_mfma_f32_16x16x16bf16_1k(va[dj], pk[0][t], o_acc[0][dj], 0, 0, 0);
                o_acc[1][dj] = __builtin_amdgcn_mfma_f32_16x16x16bf16_1k(va[dj], pk[1][t], o_acc[1][dj], 0, 0, 0);
            }
            l_acc[0] = __builtin_amdgcn_mfma_f32_16x16x16bf16_1k(v_one, pk[0][t], l_acc[0], 0, 0, 0);
            l_acc[1] = __builtin_amdgcn_mfma_f32_16x16x16bf16_1k(v_one, pk[1][t], l_acc[1], 0, 0, 0);
        }
    }

    // epilogue: transpose O^T -> O through LDS, coalesced 16B stores
    __syncthreads();
    unsigned short* Os = smem;               // reuse: 128 x 72
#pragma unroll
    for (int mi = 0; mi < 2; ++mi) {
        const float inv = 1.0f / l_acc[mi][0];
#pragma unroll
        for (int dj = 0; dj < 4; ++dj)
#pragma unroll
            for (int r = 0; r < 4; ++r)
                Os[(wave * 32 + mi * 16 + lrow) * 72 + dj * 16 + quad * 4 + r] =
                    f2bf(o_acc[mi][dj][r] * inv);
    }
    __syncthreads();
#pragma unroll
    for (int i = 0; i < 4; ++i) {
        const int idx = i * 256 + tid;
        const int row = idx >> 3, c8 = idx & 7;
        const uint4 vv = *(const uint4*)&Os[row * 72 + c8 * 8];
        *(uint4*)&O[(size_t)(q0 + row) * HDIM + h * HDSZ + c8 * 8] = vv;
    }
}

// ---------------------------------------------------------------- launcher
extern "C" void kernel_launch(void* const* d_in, const int* in_sizes, int n_in,
                              void* d_out, int out_size, void* d_ws, size_t ws_size,
                              hipStream_t stream)
{
    const float* x  = (const float*)d_in[0];
    // d_in[1] = attention_mask (exact causal) — recomputed from indices, never read
    const float* Wq = (const float*)d_in[2];
    const float* Wk = (const float*)d_in[3];
    const float* Wv = (const float*)d_in[4];
    const float* Wo = (const float*)d_in[5];
    float* out = (float*)d_out;

    unsigned short* xb   = (unsigned short*)d_ws;                // 4096*2048
    unsigned short* Wqkb = xb   + (size_t)S_LEN * HDIM;          // 2560*2048 (Wq|Wk)
    unsigned short* Wvb  = Wqkb + (size_t)QKN * HDIM;            // 512*2048
    unsigned short* Wob  = Wvb  + (size_t)KVDIM * HDIM;          // 2048*2048
    unsigned short* QKb  = Wob  + (size_t)HDIM * HDIM;           // 4096*2560 (Q|K)
    unsigned short* Vtb  = QKb  + (size_t)S_LEN * QKN;           // 512*4096 (V^T)
    unsigned short* AOb  = xb;                                   // reuse

    auto cvt = [&](const float* src, unsigned short* dst, size_t n, float scale) {
        const int n4 = (int)(n / 4);
        cvt_f32_bf16<<<(n4 + 255) / 256, 256, 0, stream>>>(src, dst, n4, scale);
    };
    // Wq pre-scaled by log2(e)/sqrt(HD): softmax runs in exp2 domain.
    cvt(x,  xb,  (size_t)S_LEN * HDIM, 1.0f);
    cvt(Wq, Wqkb, (size_t)HDIM * HDIM, 0.18033688011f);
    cvt(Wk, Wqkb + (size_t)HDIM * HDIM, (size_t)KVDIM * HDIM, 1.0f);
    cvt(Wv, Wvb, (size_t)KVDIM * HDIM, 1.0f);
    cvt(Wo, Wob, (size_t)HDIM * HDIM, 1.0f);

    // fused Q|K projection: [4096 x 2560]
    gemm_bt<true ><<<dim3(S_LEN / 128, QKN / 128), 256, 0, stream>>>(
        xb, Wqkb, QKb, S_LEN, QKN, HDIM, 1.0f);
    // V projection computed TRANSPOSED (operands swapped): V^T [512 x 4096]
    gemm_bt<true ><<<dim3(KVDIM / 128, S_LEN / 128), 256, 0, stream>>>(
        Wvb, xb, Vtb, KVDIM, S_LEN, HDIM, 1.0f);

    flash_attn<<<dim3(NHEADS, S_LEN / 128), 256, 0, stream>>>(QKb, Vtb, AOb);

    gemm_bt<false><<<dim3(S_LEN / 128, HDIM / 128), 256, 0, stream>>>(
        AOb, Wob, out, S_LEN, HDIM, HDIM, 1.0f);
}